// Round 1
// baseline (412.397 us; speedup 1.0000x reference)
//
#include <hip/hip_runtime.h>
#include <hip/hip_bf16.h>

typedef __attribute__((ext_vector_type(8))) short          s16x8;
typedef __attribute__((ext_vector_type(8))) unsigned short u16x8;
typedef __attribute__((ext_vector_type(4))) float          f4;

__device__ __forceinline__ float bf2f(unsigned short u) {
    union { unsigned int i; float f; } x; x.i = ((unsigned int)u) << 16; return x.f;
}
__device__ __forceinline__ unsigned short f2bf(float f) {
    __hip_bfloat16 h = __float2bfloat16(f);
    return *reinterpret_cast<unsigned short*>(&h);
}

// OUT[m][n] = (sum_k A[m][k] * W[n][k] + bias[n]) * scale
// A: [M][512] (fp32 or bf16-ushort), W: [512][512] fp32, OUT: [M][512] (fp32 or bf16)
template <bool AF32, bool OF32>
__global__ __launch_bounds__(256) void gemm_nt(const void* __restrict__ Ap,
                                               const float* __restrict__ W,
                                               const float* __restrict__ bias,
                                               void* __restrict__ Outp,
                                               float scale) {
    constexpr int BK = 32, KD = 512, LDT = BK + 8;  // pad 8 ushort -> 80B stride
    __shared__ unsigned short As[128][LDT];
    __shared__ unsigned short Bs[128][LDT];

    const int tid  = threadIdx.x;
    const int lane = tid & 63;
    const int wid  = tid >> 6;
    const int wm   = wid >> 1;
    const int wn   = wid & 1;
    const long m0  = (long)blockIdx.x * 128;
    const int  n0  = blockIdx.y * 128;
    const int srow = tid >> 1;         // 0..127
    const int kseg = (tid & 1) << 4;   // 0 or 16

    const float*          Af = (const float*)Ap;
    const unsigned short* Ab = (const unsigned short*)Ap;

    f4 acc[4][4];
#pragma unroll
    for (int i = 0; i < 4; ++i)
#pragma unroll
        for (int j = 0; j < 4; ++j) acc[i][j] = (f4)(0.0f);

    float fa[16];
    u16x8 ua[2];
    float fb[16];

    auto load_tile = [&](int kt) {
        if constexpr (AF32) {
#pragma unroll
            for (int j = 0; j < 4; ++j) {
                f4 v = *(const f4*)(Af + (m0 + srow) * KD + kt + kseg + j * 4);
#pragma unroll
                for (int e = 0; e < 4; ++e) fa[j * 4 + e] = v[e];
            }
        } else {
#pragma unroll
            for (int j = 0; j < 2; ++j)
                ua[j] = *(const u16x8*)(Ab + (m0 + srow) * KD + kt + kseg + j * 8);
        }
#pragma unroll
        for (int j = 0; j < 4; ++j) {
            f4 v = *(const f4*)(W + (long)(n0 + srow) * KD + kt + kseg + j * 4);
#pragma unroll
            for (int e = 0; e < 4; ++e) fb[j * 4 + e] = v[e];
        }
    };

    auto store_tile = [&]() {
        if constexpr (AF32) {
            unsigned short t[16];
#pragma unroll
            for (int j = 0; j < 16; ++j) t[j] = f2bf(fa[j]);
            *(u16x8*)&As[srow][kseg]     = *(u16x8*)&t[0];
            *(u16x8*)&As[srow][kseg + 8] = *(u16x8*)&t[8];
        } else {
            *(u16x8*)&As[srow][kseg]     = ua[0];
            *(u16x8*)&As[srow][kseg + 8] = ua[1];
        }
        unsigned short t2[16];
#pragma unroll
        for (int j = 0; j < 16; ++j) t2[j] = f2bf(fb[j]);
        *(u16x8*)&Bs[srow][kseg]     = *(u16x8*)&t2[0];
        *(u16x8*)&Bs[srow][kseg + 8] = *(u16x8*)&t2[8];
    };

    const int fr = lane & 15;          // frag row (A) / col (B) / col (D)
    const int ko = (lane >> 4) << 3;   // k-offset 0/8/16/24

    load_tile(0);
    for (int kt = 0; kt < KD; kt += BK) {
        __syncthreads();
        store_tile();
        __syncthreads();
        if (kt + BK < KD) load_tile(kt + BK);  // prefetch overlaps MFMA below
        s16x8 af[4], bf[4];
#pragma unroll
        for (int mi = 0; mi < 4; ++mi)
            af[mi] = *(const s16x8*)&As[wm * 64 + mi * 16 + fr][ko];
#pragma unroll
        for (int ni = 0; ni < 4; ++ni)
            bf[ni] = *(const s16x8*)&Bs[wn * 64 + ni * 16 + fr][ko];
#pragma unroll
        for (int mi = 0; mi < 4; ++mi)
#pragma unroll
            for (int ni = 0; ni < 4; ++ni)
                acc[mi][ni] = __builtin_amdgcn_mfma_f32_16x16x32_bf16(
                    af[mi], bf[ni], acc[mi][ni], 0, 0, 0);
    }

    const int rq = (lane >> 4) << 2;   // D row base per lane-group
#pragma unroll
    for (int ni = 0; ni < 4; ++ni) {
        const int   col = n0 + wn * 64 + ni * 16 + fr;
        const float bv  = bias[col];
#pragma unroll
        for (int mi = 0; mi < 4; ++mi) {
            const long rbase = m0 + wm * 64 + mi * 16 + rq;
#pragma unroll
            for (int r = 0; r < 4; ++r) {
                const float val = (acc[mi][ni][r] + bv) * scale;
                if constexpr (OF32)
                    ((float*)Outp)[(rbase + r) * KD + col] = val;
                else
                    ((unsigned short*)Outp)[(rbase + r) * KD + col] = f2bf(val);
            }
        }
    }
}

// One thread per (b, head, y, x). qh is pre-scaled. Layout [pix][h*32+d] bf16.
__global__ __launch_bounds__(256) void natt(const unsigned short* __restrict__ qh,
                                            const unsigned short* __restrict__ kh,
                                            const unsigned short* __restrict__ vh,
                                            const float* __restrict__ rpb,
                                            unsigned short* __restrict__ xout) {
    const int g = blockIdx.x * 256 + threadIdx.x;
    const int h = g & 15;
    const int x = (g >> 4) & 127;
    const int y = (g >> 11) & 127;
    const int b = g >> 18;

    const int winY = min(max(y - 3, 0), 121);
    const int winX = min(max(x - 3, 0), 121);
    const int pbY  = (y < 3) ? (6 - y) : ((y >= 125) ? (127 - y) : 3);
    const int pbX  = (x < 3) ? (6 - x) : ((x >= 125) ? (127 - x) : 3);

    const long pix = ((long)b * 128 + y) * 128 + x;
    const unsigned short* qp = qh + pix * 512 + h * 32;

    float qv[32];
#pragma unroll
    for (int j = 0; j < 4; ++j) {
        u16x8 v = *(const u16x8*)(qp + j * 8);
#pragma unroll
        for (int e = 0; e < 8; ++e) qv[j * 8 + e] = bf2f(v[e]);
    }

    float logit[49];
    const float* rp = rpb + h * 169 + pbY * 13 + pbX;
#pragma unroll
    for (int a = 0; a < 7; ++a) {
        const long rowbase = ((long)b * 128 + winY + a) * 128 + winX;
#pragma unroll
        for (int c = 0; c < 7; ++c) {
            const unsigned short* kp = kh + (rowbase + c) * 512 + h * 32;
            float s = 0.f;
#pragma unroll
            for (int j = 0; j < 4; ++j) {
                u16x8 v = *(const u16x8*)(kp + j * 8);
#pragma unroll
                for (int e = 0; e < 8; ++e) s = fmaf(qv[j * 8 + e], bf2f(v[e]), s);
            }
            logit[a * 7 + c] = s + rp[a * 13 + c];
        }
    }

    float m = logit[0];
#pragma unroll
    for (int i = 1; i < 49; ++i) m = fmaxf(m, logit[i]);
    float sum = 0.f;
#pragma unroll
    for (int i = 0; i < 49; ++i) {
        float p = exp2f((logit[i] - m) * 1.4426950408889634f);
        logit[i] = p;
        sum += p;
    }
    const float rinv = 1.f / sum;

    float acc[32];
#pragma unroll
    for (int d = 0; d < 32; ++d) acc[d] = 0.f;
#pragma unroll
    for (int a = 0; a < 7; ++a) {
        const long rowbase = ((long)b * 128 + winY + a) * 128 + winX;
#pragma unroll
        for (int c = 0; c < 7; ++c) {
            const unsigned short* vp = vh + (rowbase + c) * 512 + h * 32;
            const float w = logit[a * 7 + c] * rinv;
#pragma unroll
            for (int j = 0; j < 4; ++j) {
                u16x8 v = *(const u16x8*)(vp + j * 8);
#pragma unroll
                for (int e = 0; e < 8; ++e)
                    acc[j * 8 + e] = fmaf(w, bf2f(v[e]), acc[j * 8 + e]);
            }
        }
    }

    unsigned short* op = xout + pix * 512 + h * 32;
#pragma unroll
    for (int j = 0; j < 4; ++j) {
        unsigned short t[8];
#pragma unroll
        for (int e = 0; e < 8; ++e) t[e] = f2bf(acc[j * 8 + e]);
        *(u16x8*)(op + j * 8) = *(u16x8*)t;
    }
}

extern "C" void kernel_launch(void* const* d_in, const int* in_sizes, int n_in,
                              void* d_out, int out_size, void* d_ws, size_t ws_size,
                              hipStream_t stream) {
    const float* q   = (const float*)d_in[0];
    const float* k   = (const float*)d_in[1];
    const float* v   = (const float*)d_in[2];
    const float* wq  = (const float*)d_in[3];
    const float* bq  = (const float*)d_in[4];
    const float* wk  = (const float*)d_in[5];
    const float* bk  = (const float*)d_in[6];
    const float* wv  = (const float*)d_in[7];
    const float* bv  = (const float*)d_in[8];
    const float* rpb = (const float*)d_in[9];
    const float* wo  = (const float*)d_in[10];
    const float* bo  = (const float*)d_in[11];

    const long P = 2l * 128 * 128;  // 32768 pixels
    unsigned short* qh = (unsigned short*)d_ws;
    unsigned short* kh = qh + P * 512;
    unsigned short* vh = kh + P * 512;
    unsigned short* xb = vh + P * 512;

    const dim3 gg(256, 4, 1);  // M/128 x N/128
    const float scale = 0.17677669529663687f;  // 32^-0.5

    gemm_nt<true, false><<<gg, 256, 0, stream>>>(q, wq, bq, qh, scale);
    gemm_nt<true, false><<<gg, 256, 0, stream>>>(k, wk, bk, kh, 1.0f);
    gemm_nt<true, false><<<gg, 256, 0, stream>>>(v, wv, bv, vh, 1.0f);

    natt<<<2048, 256, 0, stream>>>(qh, kh, vh, rpb, xb);

    gemm_nt<false, true><<<gg, 256, 0, stream>>>(xb, wo, bo, (float*)d_out, 1.0f);
}

// Round 2
// 315.047 us; speedup vs baseline: 1.3090x; 1.3090x over previous
//
#include <hip/hip_runtime.h>
#include <hip/hip_bf16.h>

typedef __attribute__((ext_vector_type(8))) short          s16x8;
typedef __attribute__((ext_vector_type(8))) unsigned short u16x8;
typedef __attribute__((ext_vector_type(4))) float          f4;

__device__ __forceinline__ float bf2f(unsigned short u) {
    union { unsigned int i; float f; } x; x.i = ((unsigned int)u) << 16; return x.f;
}
__device__ __forceinline__ unsigned short f2bf(float f) {
    __hip_bfloat16 h = __float2bfloat16(f);
    return *reinterpret_cast<unsigned short*>(&h);
}

// OUT[m][n] = (sum_k A[m][k] * W[n][k] + bias[n]) * scale
// Grid: (N/128, M/128) — x-fastest dispatch keeps the 4 N-tile blocks of one
// A-tile adjacent in time so A is served from L2/LLC instead of re-fetched.
template <bool AF32, bool OF32>
__global__ __launch_bounds__(256) void gemm_nt(const void* __restrict__ Ap,
                                               const float* __restrict__ W,
                                               const float* __restrict__ bias,
                                               void* __restrict__ Outp,
                                               float scale) {
    constexpr int BK = 32, KD = 512, LDT = BK + 8;  // pad 8 ushort -> 80B stride
    __shared__ unsigned short As[128][LDT];
    __shared__ unsigned short Bs[128][LDT];

    const int tid  = threadIdx.x;
    const int lane = tid & 63;
    const int wid  = tid >> 6;
    const int wm   = wid >> 1;
    const int wn   = wid & 1;
    const int  n0  = blockIdx.x * 128;
    const long m0  = (long)blockIdx.y * 128;
    const int srow = tid >> 1;         // 0..127
    const int kseg = (tid & 1) << 4;   // 0 or 16

    const float*          Af = (const float*)Ap;
    const unsigned short* Ab = (const unsigned short*)Ap;

    f4 acc[4][4];
#pragma unroll
    for (int i = 0; i < 4; ++i)
#pragma unroll
        for (int j = 0; j < 4; ++j) acc[i][j] = (f4)(0.0f);

    float fa[16];
    u16x8 ua[2];
    float fb[16];

    auto load_tile = [&](int kt) {
        if constexpr (AF32) {
#pragma unroll
            for (int j = 0; j < 4; ++j) {
                f4 v = *(const f4*)(Af + (m0 + srow) * KD + kt + kseg + j * 4);
#pragma unroll
                for (int e = 0; e < 4; ++e) fa[j * 4 + e] = v[e];
            }
        } else {
#pragma unroll
            for (int j = 0; j < 2; ++j)
                ua[j] = *(const u16x8*)(Ab + (m0 + srow) * KD + kt + kseg + j * 8);
        }
#pragma unroll
        for (int j = 0; j < 4; ++j) {
            f4 v = *(const f4*)(W + (long)(n0 + srow) * KD + kt + kseg + j * 4);
#pragma unroll
            for (int e = 0; e < 4; ++e) fb[j * 4 + e] = v[e];
        }
    };

    auto store_tile = [&]() {
        if constexpr (AF32) {
            unsigned short t[16];
#pragma unroll
            for (int j = 0; j < 16; ++j) t[j] = f2bf(fa[j]);
            *(u16x8*)&As[srow][kseg]     = *(u16x8*)&t[0];
            *(u16x8*)&As[srow][kseg + 8] = *(u16x8*)&t[8];
        } else {
            *(u16x8*)&As[srow][kseg]     = ua[0];
            *(u16x8*)&As[srow][kseg + 8] = ua[1];
        }
        unsigned short t2[16];
#pragma unroll
        for (int j = 0; j < 16; ++j) t2[j] = f2bf(fb[j]);
        *(u16x8*)&Bs[srow][kseg]     = *(u16x8*)&t2[0];
        *(u16x8*)&Bs[srow][kseg + 8] = *(u16x8*)&t2[8];
    };

    const int fr = lane & 15;          // frag row (A) / col (B) / col (D)
    const int ko = (lane >> 4) << 3;   // k-offset 0/8/16/24

    load_tile(0);
    for (int kt = 0; kt < KD; kt += BK) {
        __syncthreads();
        store_tile();
        __syncthreads();
        if (kt + BK < KD) load_tile(kt + BK);  // prefetch overlaps MFMA below
        s16x8 af[4], bf[4];
#pragma unroll
        for (int mi = 0; mi < 4; ++mi)
            af[mi] = *(const s16x8*)&As[wm * 64 + mi * 16 + fr][ko];
#pragma unroll
        for (int ni = 0; ni < 4; ++ni)
            bf[ni] = *(const s16x8*)&Bs[wn * 64 + ni * 16 + fr][ko];
#pragma unroll
        for (int mi = 0; mi < 4; ++mi)
#pragma unroll
            for (int ni = 0; ni < 4; ++ni)
                acc[mi][ni] = __builtin_amdgcn_mfma_f32_16x16x32_bf16(
                    af[mi], bf[ni], acc[mi][ni], 0, 0, 0);
    }

    const int rq = (lane >> 4) << 2;   // D row base per lane-group
#pragma unroll
    for (int ni = 0; ni < 4; ++ni) {
        const int   col = n0 + wn * 64 + ni * 16 + fr;
        const float bv  = bias[col];
#pragma unroll
        for (int mi = 0; mi < 4; ++mi) {
            const long rbase = m0 + wm * 64 + mi * 16 + rq;
#pragma unroll
            for (int r = 0; r < 4; ++r) {
                const float val = (acc[mi][ni][r] + bv) * scale;
                if constexpr (OF32)
                    ((float*)Outp)[(rbase + r) * KD + col] = val;
                else
                    ((unsigned short*)Outp)[(rbase + r) * KD + col] = f2bf(val);
            }
        }
    }
}

// LDS-tiled NAT: one block per (b, head, 16x16 pixel tile).
// Stage the 22x22 key halo (bf16, 32 dims) into LDS; two phases share one
// 38.7 KB buffer (K for logits, then V for the weighted sum).
__global__ __launch_bounds__(256) void natt(const unsigned short* __restrict__ qh,
                                            const unsigned short* __restrict__ kh,
                                            const unsigned short* __restrict__ vh,
                                            const float* __restrict__ rpb,
                                            unsigned short* __restrict__ xout) {
    constexpr int LDK = 40;                 // shorts per key row (80 B, 16B-aligned)
    __shared__ unsigned short KV[484][LDK]; // 38720 B
    __shared__ float Rs[169];

    const int tid = threadIdx.x;
    const int h   = blockIdx.z & 15;
    const int b   = blockIdx.z >> 4;
    const int x0  = blockIdx.x * 16;
    const int y0  = blockIdx.y * 16;
    const int ux0 = min(max(x0 - 3, 0), 106);
    const int uy0 = min(max(y0 - 3, 0), 106);
    const int tx  = tid & 15;
    const int ty  = tid >> 4;
    const int x   = x0 + tx;
    const int y   = y0 + ty;

    if (tid < 169) Rs[tid] = rpb[h * 169 + tid];

    const long imgbase = (long)b * 128 * 128;

    // stage K halo
#pragma unroll 2
    for (int kk = tid; kk < 484; kk += 256) {
        const int ky = uy0 + kk / 22;
        const int kx = ux0 + kk % 22;
        const unsigned short* src = kh + (imgbase + ky * 128 + kx) * 512 + h * 32;
#pragma unroll
        for (int j = 0; j < 4; ++j)
            *(u16x8*)&KV[kk][j * 8] = *(const u16x8*)(src + j * 8);
    }

    // load q (overlaps staging)
    const long pix = imgbase + y * 128 + x;
    const unsigned short* qp = qh + pix * 512 + h * 32;
    float qv[32];
#pragma unroll
    for (int j = 0; j < 4; ++j) {
        u16x8 v = *(const u16x8*)(qp + j * 8);
#pragma unroll
        for (int e = 0; e < 8; ++e) qv[j * 8 + e] = bf2f(v[e]);
    }

    const int myy = min(max(y - 3, 0), 121) - uy0;   // 0..15
    const int myx = min(max(x - 3, 0), 121) - ux0;   // 0..15
    const int pbY = (y < 3) ? (6 - y) : ((y >= 125) ? (127 - y) : 3);
    const int pbX = (x < 3) ? (6 - x) : ((x >= 125) ? (127 - x) : 3);

    __syncthreads();

    float logit[49];
#pragma unroll
    for (int a = 0; a < 7; ++a) {
        const int rowk = (myy + a) * 22 + myx;
#pragma unroll
        for (int c = 0; c < 7; ++c) {
            const unsigned short* kp = &KV[rowk + c][0];
            float s = 0.f;
#pragma unroll
            for (int j = 0; j < 4; ++j) {
                u16x8 v = *(const u16x8*)(kp + j * 8);
#pragma unroll
                for (int e = 0; e < 8; ++e) s = fmaf(qv[j * 8 + e], bf2f(v[e]), s);
            }
            logit[a * 7 + c] = s + Rs[(pbY + a) * 13 + pbX + c];
        }
    }

    float m = logit[0];
#pragma unroll
    for (int i = 1; i < 49; ++i) m = fmaxf(m, logit[i]);
    float sum = 0.f;
#pragma unroll
    for (int i = 0; i < 49; ++i) {
        float p = exp2f((logit[i] - m) * 1.4426950408889634f);
        logit[i] = p;
        sum += p;
    }
    const float rinv = 1.f / sum;
#pragma unroll
    for (int i = 0; i < 49; ++i) logit[i] *= rinv;

    __syncthreads();  // everyone done reading K

    // stage V halo into the same buffer
#pragma unroll 2
    for (int kk = tid; kk < 484; kk += 256) {
        const int ky = uy0 + kk / 22;
        const int kx = ux0 + kk % 22;
        const unsigned short* src = vh + (imgbase + ky * 128 + kx) * 512 + h * 32;
#pragma unroll
        for (int j = 0; j < 4; ++j)
            *(u16x8*)&KV[kk][j * 8] = *(const u16x8*)(src + j * 8);
    }
    __syncthreads();

    float acc[32];
#pragma unroll
    for (int d = 0; d < 32; ++d) acc[d] = 0.f;
#pragma unroll
    for (int a = 0; a < 7; ++a) {
        const int rowk = (myy + a) * 22 + myx;
#pragma unroll
        for (int c = 0; c < 7; ++c) {
            const unsigned short* vp = &KV[rowk + c][0];
            const float w = logit[a * 7 + c];
#pragma unroll
            for (int j = 0; j < 4; ++j) {
                u16x8 v = *(const u16x8*)(vp + j * 8);
#pragma unroll
                for (int e = 0; e < 8; ++e)
                    acc[j * 8 + e] = fmaf(w, bf2f(v[e]), acc[j * 8 + e]);
            }
        }
    }

    unsigned short* op = xout + pix * 512 + h * 32;
#pragma unroll
    for (int j = 0; j < 4; ++j) {
        unsigned short t[8];
#pragma unroll
        for (int e = 0; e < 8; ++e) t[e] = f2bf(acc[j * 8 + e]);
        *(u16x8*)(op + j * 8) = *(u16x8*)t;
    }
}

extern "C" void kernel_launch(void* const* d_in, const int* in_sizes, int n_in,
                              void* d_out, int out_size, void* d_ws, size_t ws_size,
                              hipStream_t stream) {
    const float* q   = (const float*)d_in[0];
    const float* k   = (const float*)d_in[1];
    const float* v   = (const float*)d_in[2];
    const float* wq  = (const float*)d_in[3];
    const float* bq  = (const float*)d_in[4];
    const float* wk  = (const float*)d_in[5];
    const float* bk  = (const float*)d_in[6];
    const float* wv  = (const float*)d_in[7];
    const float* bv  = (const float*)d_in[8];
    const float* rpb = (const float*)d_in[9];
    const float* wo  = (const float*)d_in[10];
    const float* bo  = (const float*)d_in[11];

    const long P = 2l * 128 * 128;  // 32768 pixels
    unsigned short* qh = (unsigned short*)d_ws;
    unsigned short* kh = qh + P * 512;
    unsigned short* vh = kh + P * 512;
    unsigned short* xb = vh + P * 512;

    const dim3 gg(4, 256, 1);  // N/128 x M/128  (x-fastest -> A-tile reuse)
    const float scale = 0.17677669529663687f;  // 32^-0.5

    gemm_nt<true, false><<<gg, 256, 0, stream>>>(q, wq, bq, qh, scale);
    gemm_nt<true, false><<<gg, 256, 0, stream>>>(k, wk, bk, kh, 1.0f);
    gemm_nt<true, false><<<gg, 256, 0, stream>>>(v, wv, bv, vh, 1.0f);

    natt<<<dim3(8, 8, 32), 256, 0, stream>>>(qh, kh, vh, rpb, xb);

    gemm_nt<false, true><<<gg, 256, 0, stream>>>(xb, wo, bo, (float*)d_out, 1.0f);
}